// Round 2
// baseline (445.197 us; speedup 1.0000x reference)
//
#include <hip/hip_runtime.h>

// SparseJL: out[n,o] = sum_k x[n,k] * Phi[o,k]
// x: (16384, 4096) fp32, Phi: (1024, 4096) fp32 with s=10 nnz/col (~1% dense).
// R2: bf16-packed LDS x-tile (8 rows per ds_read_b128) + 1024-thread blocks.
// R3: persistent blocks (1/CU) + double-buffered 128KB LDS + async-stage split:
//     next tile's global loads issue BEFORE the compute loop (sched_barrier pin),
//     pack+ds_write after. Converts stage->sync->compute serialization into
//     max(stage, compute) pipeline. ent/x pipeline deepened to 3/2 because
//     occupancy drops to 4 waves/SIMD.
// R4: identical resubmit — R3 bench died to container acquire failure (no
//     kernel error, no profile); design audit found no OOB/hang/LDS hazard.

#define IN_DIM 4096
#define OUT_DIM 1024
#define NROWS 16384
#define RPB 8       // rows of x per tile (8 bf16 = one uint4 per k)
#define MAXNZ 96    // nnz/row: mean 40, sigma 6.3 -> 93 is ~8.4 sigma; safe
#define NBLK 256    // persistent blocks, 1 per CU (128 KB LDS forces this)
#define TILES (NROWS / RPB)       // 2048
#define TPB_TILES (TILES / NBLK)  // 8 tiles per block

// ---------------------------------------------------------------------------
// Kernel 1: build j-major ELL from dense Phi.
//   ent[j*OUT_DIM + o] = { k, bits(v) } for j < cnt[o], then 3 zero sentinels
// j-major so lanes (consecutive o) load consecutive 8B -> coalesced.
// ---------------------------------------------------------------------------
__global__ __launch_bounds__(256) void build_sparse(const float* __restrict__ Phi,
                                                    int* __restrict__ cnt,
                                                    int2* __restrict__ ent) {
    const int o = blockIdx.x;
    __shared__ int lcnt;
    if (threadIdx.x == 0) lcnt = 0;
    __syncthreads();
    const float* row = Phi + (size_t)o * IN_DIM;
    for (int k = threadIdx.x; k < IN_DIM; k += 256) {
        float v = row[k];
        if (v != 0.0f) {
            int p = atomicAdd(&lcnt, 1);
            if (p < MAXNZ - 3)
                ent[(size_t)p * OUT_DIM + o] = make_int2(k, __float_as_int(v));
        }
    }
    __syncthreads();
    int c = lcnt;
    if (c > MAXNZ - 3) c = MAXNZ - 3;
    // zero sentinels: software pipeline reads up to ent[(c+2)*OUT_DIM + o]
    if (threadIdx.x < 3)
        ent[(size_t)(c + threadIdx.x) * OUT_DIM + o] = make_int2(0, 0);
    if (threadIdx.x == 0) cnt[o] = c;
}

// ---------------------------------------------------------------------------
// Kernel 2: sparse JL product. Persistent: one block per CU, 8 tiles each.
// LDS: xt[2][k] = uint4 packing bf16(x[n0..n0+7][k]) -> 2 x 64 KB double buffer.
// Per tile: {issue next-tile loads} || {compute current} -> pack+write -> sync.
// ---------------------------------------------------------------------------
__device__ __forceinline__ unsigned bf16_rne(float f) {
    unsigned u = __float_as_uint(f);
    return (u + 0x7fffu + ((u >> 16) & 1u)) >> 16;
}
__device__ __forceinline__ unsigned pack2(float lo, float hi) {
    return bf16_rne(lo) | (bf16_rne(hi) << 16);
}
__device__ __forceinline__ float blo(unsigned d) { return __uint_as_float(d << 16); }
__device__ __forceinline__ float bhi(unsigned d) { return __uint_as_float(d & 0xffff0000u); }

__global__ __launch_bounds__(1024, 4) void jl_main(const float* __restrict__ x,
                                                   const int* __restrict__ cnt,
                                                   const int2* __restrict__ ent,
                                                   float* __restrict__ out) {
    __shared__ uint4 xt[2][IN_DIM];  // 128 KB: double-buffered 8-row bf16 tiles
    const int tid = threadIdx.x;
    const int o = tid;               // each thread owns one output column
    const int c = cnt[o];            // loaded once, reused for all 8 tiles
    const int2* ep = ent + o;
    const int2* ep3 = ep + 3 * OUT_DIM;
    const int t0 = blockIdx.x * TPB_TILES;

    // ---- prologue: stage tile 0 into buffer 0
    {
        const float* xr = x + (size_t)t0 * RPB * IN_DIM + tid;
        float rs[4][8];
#pragma unroll
        for (int i = 0; i < 4; ++i)
#pragma unroll
            for (int r = 0; r < 8; ++r)
                rs[i][r] = xr[(size_t)r * IN_DIM + i * 1024];
#pragma unroll
        for (int i = 0; i < 4; ++i) {
            uint4 w;
            w.x = pack2(rs[i][0], rs[i][1]);
            w.y = pack2(rs[i][2], rs[i][3]);
            w.z = pack2(rs[i][4], rs[i][5]);
            w.w = pack2(rs[i][6], rs[i][7]);
            // write bank-group = tid&7 -> all 8 groups hit evenly, minimal conflict
            xt[0][tid + i * 1024] = w;
        }
    }
    __syncthreads();

    int cur = 0;
#pragma unroll 1
    for (int it = 0; it < TPB_TILES; ++it) {
        // ---- A) issue next tile's staging loads into registers (in flight
        //         across the whole compute phase -> HBM hidden under compute)
        float rs[4][8];
        const bool have_next = (it + 1 < TPB_TILES);  // block-uniform
        if (have_next) {
            const float* xr = x + (size_t)(t0 + it + 1) * RPB * IN_DIM + tid;
#pragma unroll
            for (int i = 0; i < 4; ++i)
#pragma unroll
                for (int r = 0; r < 8; ++r)
                    rs[i][r] = xr[(size_t)r * IN_DIM + i * 1024];
        }
        __builtin_amdgcn_sched_barrier(0);  // pin: loads stay issued before compute

        // ---- B) compute current tile. Depth-3 ent / depth-2 x pipeline
        //         (zero sentinels at c,c+1,c+2 make lookahead j+3 safe).
        const uint4* xb = xt[cur];
        int2 e0 = ep[0];
        int2 e1 = ep[OUT_DIM];
        int2 e2 = ep[2 * OUT_DIM];
        uint4 x0 = xb[e0.x];
        uint4 x1 = xb[e1.x];

        float a0 = 0.f, a1 = 0.f, a2 = 0.f, a3 = 0.f;
        float a4 = 0.f, a5 = 0.f, a6 = 0.f, a7 = 0.f;
        for (int j = 0; j < c; ++j) {
            int2 e3 = ep3[(size_t)j * OUT_DIM];  // global prefetch (j+3), L2-resident
            uint4 x2 = xb[e2.x];                 // LDS read (j+2)
            float v = __int_as_float(e0.y);      // FMA (j): 8 rows
            a0 = fmaf(v, blo(x0.x), a0);
            a1 = fmaf(v, bhi(x0.x), a1);
            a2 = fmaf(v, blo(x0.y), a2);
            a3 = fmaf(v, bhi(x0.y), a3);
            a4 = fmaf(v, blo(x0.z), a4);
            a5 = fmaf(v, bhi(x0.z), a5);
            a6 = fmaf(v, blo(x0.w), a6);
            a7 = fmaf(v, bhi(x0.w), a7);
            e0 = e1; e1 = e2; e2 = e3;
            x0 = x1; x1 = x2;
        }

        float* op = out + (size_t)(t0 + it) * RPB * OUT_DIM + o;  // coalesced
        op[0 * OUT_DIM] = a0;
        op[1 * OUT_DIM] = a1;
        op[2 * OUT_DIM] = a2;
        op[3 * OUT_DIM] = a3;
        op[4 * OUT_DIM] = a4;
        op[5 * OUT_DIM] = a5;
        op[6 * OUT_DIM] = a6;
        op[7 * OUT_DIM] = a7;

        // ---- C) pack + write next buffer (compiler inserts vmcnt wait on rs use)
        if (have_next) {
#pragma unroll
            for (int i = 0; i < 4; ++i) {
                uint4 w;
                w.x = pack2(rs[i][0], rs[i][1]);
                w.y = pack2(rs[i][2], rs[i][3]);
                w.z = pack2(rs[i][4], rs[i][5]);
                w.w = pack2(rs[i][6], rs[i][7]);
                xt[cur ^ 1][tid + i * 1024] = w;
            }
        }
        __syncthreads();  // one barrier per tile: next buffer ready, this one free
        cur ^= 1;
    }
}

extern "C" void kernel_launch(void* const* d_in, const int* in_sizes, int n_in,
                              void* d_out, int out_size, void* d_ws, size_t ws_size,
                              hipStream_t stream) {
    const float* x   = (const float*)d_in[0];   // 16384 x 4096
    const float* Phi = (const float*)d_in[1];   // 1024 x 4096
    float* out = (float*)d_out;                 // 16384 x 1024

    // ws layout: [cnt: 1024 ints = 4 KB][ent: MAXNZ*1024 int2 = 768 KB]
    int*  cnt = (int*)d_ws;
    int2* ent = (int2*)((char*)d_ws + OUT_DIM * sizeof(int));

    build_sparse<<<OUT_DIM, 256, 0, stream>>>(Phi, cnt, ent);
    jl_main<<<NBLK, 1024, 0, stream>>>(x, cnt, ent, out);
}

// Round 3
// 422.935 us; speedup vs baseline: 1.0526x; 1.0526x over previous
//
#include <hip/hip_runtime.h>

// SparseJL: out[n,o] = sum_k x[n,k] * Phi[o,k]
// x: (16384, 4096) fp32, Phi: (1024, 4096) fp32 with s=10 nnz/col (~1% dense).
// R2: bf16-packed LDS x-tile (8 rows per ds_read_b128) + 1024-thread blocks.
// R3: persistent 1-block/CU double-buffer -> REGRESSED (142->161 us): kernel is
//     latency-bound (VALU 35%, LDS 26%, HBM 17%); halving waves/SIMD hurt more
//     than stage/compute overlap helped.
// R5: revert to R2 occupancy (64 KB LDS, 2 blocks/CU, 32 waves/CU) and DOUBLE
//     per-wave memory-level parallelism: 2 entries/iteration, rotated pipeline
//     with 2 ds_read_b128 + 2 ent loads in flight. 6 zero sentinels make the
//     paired tail + deep prefetch branch-free (sentinel v=0, k=0 is harmless).

#define IN_DIM 4096
#define OUT_DIM 1024
#define NROWS 16384
#define RPB 8      // rows of x per block (8 bf16 = one uint4 per k)
#define MAXNZ 96   // nnz/row: mean 40, sigma 6.3 -> 90 is ~7.9 sigma; safe

// ---------------------------------------------------------------------------
// Kernel 1: build j-major ELL from dense Phi.
//   ent[j*OUT_DIM + o] = { k, bits(v) } for j < cnt[o], then 6 zero sentinels
// j-major so lanes (consecutive o) load consecutive 8B -> coalesced.
// ---------------------------------------------------------------------------
__global__ __launch_bounds__(256) void build_sparse(const float* __restrict__ Phi,
                                                    int* __restrict__ cnt,
                                                    int2* __restrict__ ent) {
    const int o = blockIdx.x;
    __shared__ int lcnt;
    if (threadIdx.x == 0) lcnt = 0;
    __syncthreads();
    const float* row = Phi + (size_t)o * IN_DIM;
    for (int k = threadIdx.x; k < IN_DIM; k += 256) {
        float v = row[k];
        if (v != 0.0f) {
            int p = atomicAdd(&lcnt, 1);
            if (p < MAXNZ - 6)
                ent[(size_t)p * OUT_DIM + o] = make_int2(k, __float_as_int(v));
        }
    }
    __syncthreads();
    int c = lcnt;
    if (c > MAXNZ - 6) c = MAXNZ - 6;
    // zero sentinels: unrolled pipeline prefetches up to ent[(c+4)*OUT_DIM + o]
    // and the paired tail may execute one sentinel entry (v=0 -> no-op FMA).
    if (threadIdx.x < 6)
        ent[(size_t)(c + threadIdx.x) * OUT_DIM + o] = make_int2(0, 0);
    if (threadIdx.x == 0) cnt[o] = c;
}

// ---------------------------------------------------------------------------
// Kernel 2: sparse JL product. One block = 8 rows of x, 1024 threads.
// LDS: xt[k] = uint4 packing bf16(x[n0..n0+7][k]) -> 64 KB, 2 blocks/CU,
//   32 waves/CU. Two entries per iteration: 2 ds_read_b128 + 2 ent loads in
//   flight per wave -> half the exposed latency per FMA vs R2.
// ---------------------------------------------------------------------------
__device__ __forceinline__ unsigned bf16_rne(float f) {
    unsigned u = __float_as_uint(f);
    return (u + 0x7fffu + ((u >> 16) & 1u)) >> 16;
}
__device__ __forceinline__ unsigned pack2(float lo, float hi) {
    return bf16_rne(lo) | (bf16_rne(hi) << 16);
}
__device__ __forceinline__ float blo(unsigned d) { return __uint_as_float(d << 16); }
__device__ __forceinline__ float bhi(unsigned d) { return __uint_as_float(d & 0xffff0000u); }

__global__ __launch_bounds__(1024, 8) void jl_main(const float* __restrict__ x,
                                                   const int* __restrict__ cnt,
                                                   const int2* __restrict__ ent,
                                                   float* __restrict__ out) {
    __shared__ uint4 xt[IN_DIM];  // 64 KB: 8 bf16 rows packed per k
    const int tid = threadIdx.x;
    const size_t n0 = (size_t)blockIdx.x * RPB;
    const float* xr = x + n0 * IN_DIM;

    // ---- stage: k = tid + i*1024 -> ds_write_b128 lane-contiguous (optimal)
#pragma unroll
    for (int i = 0; i < IN_DIM / 1024; ++i) {
        const int k = tid + i * 1024;
        float r0 = xr[k];
        float r1 = xr[1 * IN_DIM + k];
        float r2 = xr[2 * IN_DIM + k];
        float r3 = xr[3 * IN_DIM + k];
        float r4 = xr[4 * IN_DIM + k];
        float r5 = xr[5 * IN_DIM + k];
        float r6 = xr[6 * IN_DIM + k];
        float r7 = xr[7 * IN_DIM + k];
        uint4 w;
        w.x = pack2(r0, r1);
        w.y = pack2(r2, r3);
        w.z = pack2(r4, r5);
        w.w = pack2(r6, r7);
        xt[k] = w;
    }
    __syncthreads();

    // ---- compute: each thread owns one output column o = tid
    const int o = tid;
    const int c = cnt[o];
    const int2* ep = ent + o;

    // rotated pipeline, 2 entries/iter: ent depth 4..5, x depth 2..3
    int2 e0 = ep[0];
    int2 e1 = ep[1 * OUT_DIM];
    int2 e2 = ep[2 * OUT_DIM];
    int2 e3 = ep[3 * OUT_DIM];
    uint4 x0 = xt[e0.x];
    uint4 x1 = xt[e1.x];

    float a0 = 0.f, a1 = 0.f, a2 = 0.f, a3 = 0.f;
    float a4 = 0.f, a5 = 0.f, a6 = 0.f, a7 = 0.f;
    const int2* ep4 = ep + 4 * OUT_DIM;
    const int2* ep5 = ep + 5 * OUT_DIM;
    for (int j = 0; j < c; j += 2) {
        int2 e4 = ep4[(size_t)j * OUT_DIM];  // global prefetch (j+4), L2-resident
        int2 e5 = ep5[(size_t)j * OUT_DIM];  // global prefetch (j+5)
        uint4 xa = xt[e2.x];                 // LDS read (j+2)
        uint4 xb = xt[e3.x];                 // LDS read (j+3)
        float v0 = __int_as_float(e0.y);     // FMA (j): 8 rows
        a0 = fmaf(v0, blo(x0.x), a0);
        a1 = fmaf(v0, bhi(x0.x), a1);
        a2 = fmaf(v0, blo(x0.y), a2);
        a3 = fmaf(v0, bhi(x0.y), a3);
        a4 = fmaf(v0, blo(x0.z), a4);
        a5 = fmaf(v0, bhi(x0.z), a5);
        a6 = fmaf(v0, blo(x0.w), a6);
        a7 = fmaf(v0, bhi(x0.w), a7);
        float v1 = __int_as_float(e1.y);     // FMA (j+1): 8 rows (sentinel-safe)
        a0 = fmaf(v1, blo(x1.x), a0);
        a1 = fmaf(v1, bhi(x1.x), a1);
        a2 = fmaf(v1, blo(x1.y), a2);
        a3 = fmaf(v1, bhi(x1.y), a3);
        a4 = fmaf(v1, blo(x1.z), a4);
        a5 = fmaf(v1, bhi(x1.z), a5);
        a6 = fmaf(v1, blo(x1.w), a6);
        a7 = fmaf(v1, bhi(x1.w), a7);
        e0 = e2; e1 = e3; e2 = e4; e3 = e5;
        x0 = xa; x1 = xb;
    }

    float* op = out + n0 * OUT_DIM + o;  // coalesced: lanes -> consecutive o
    op[0 * OUT_DIM] = a0;
    op[1 * OUT_DIM] = a1;
    op[2 * OUT_DIM] = a2;
    op[3 * OUT_DIM] = a3;
    op[4 * OUT_DIM] = a4;
    op[5 * OUT_DIM] = a5;
    op[6 * OUT_DIM] = a6;
    op[7 * OUT_DIM] = a7;
}

extern "C" void kernel_launch(void* const* d_in, const int* in_sizes, int n_in,
                              void* d_out, int out_size, void* d_ws, size_t ws_size,
                              hipStream_t stream) {
    const float* x   = (const float*)d_in[0];   // 16384 x 4096
    const float* Phi = (const float*)d_in[1];   // 1024 x 4096
    float* out = (float*)d_out;                 // 16384 x 1024

    // ws layout: [cnt: 1024 ints = 4 KB][ent: MAXNZ*1024 int2 = 768 KB]
    int*  cnt = (int*)d_ws;
    int2* ent = (int2*)((char*)d_ws + OUT_DIM * sizeof(int));

    build_sparse<<<OUT_DIM, 256, 0, stream>>>(Phi, cnt, ent);
    jl_main<<<NROWS / RPB, 1024, 0, stream>>>(x, cnt, ent, out);
}